// Round 1
// baseline (28.175 us; speedup 1.0000x reference)
//
#include <hip/hip_runtime.h>
#include <hip/hip_bf16.h>
#include <math.h>

// Problem constants
#define NB 8
#define NP 1024
#define ND 4
#define ITILE 32            // i-rows per pair-block
#define NTILES (NP / ITILE) // 32 pair-blocks per batch

#define INV_SQRT_2PI 0.3989422804014327f
#define RK 0.282095f
// pilot = 1.0592 * std * n^(-1/(4+d)) ; n=1024,d=4 -> 1024^(-0.125)=2^-1.25
#define N_POW (0.42044820762685725f)

// ws layout (floats):
//  [0 .. 31]            inv_pilot[b][d]
//  [32 .. 63]           pilot[b][d]
//  [64 .. 64+256*8)     partials[(b*NTILES+tile)*8 + k]  (k: 0..3 = s2 dims, 4..7 = s3 dims)
#define WS_PARTIAL 64

__global__ __launch_bounds__(256) void bw_stats_kernel(const float* __restrict__ p,
                                                       float* __restrict__ ws) {
    int b = blockIdx.x;
    const float4* pb = (const float4*)(p + (size_t)b * NP * ND);

    float s[4] = {0.f, 0.f, 0.f, 0.f};
    float ss[4] = {0.f, 0.f, 0.f, 0.f};
    for (int i = threadIdx.x; i < NP; i += 256) {
        float4 v = pb[i];
        s[0] += v.x; s[1] += v.y; s[2] += v.z; s[3] += v.w;
        ss[0] += v.x * v.x; ss[1] += v.y * v.y; ss[2] += v.z * v.z; ss[3] += v.w * v.w;
    }

    float vals[8] = {s[0], s[1], s[2], s[3], ss[0], ss[1], ss[2], ss[3]};
#pragma unroll
    for (int off = 32; off > 0; off >>= 1) {
#pragma unroll
        for (int k = 0; k < 8; ++k) vals[k] += __shfl_down(vals[k], off, 64);
    }

    __shared__ float red[4][8];
    int wave = threadIdx.x >> 6;
    int lane = threadIdx.x & 63;
    if (lane == 0) {
#pragma unroll
        for (int k = 0; k < 8; ++k) red[wave][k] = vals[k];
    }
    __syncthreads();

    if (threadIdx.x < ND) {
        int d = threadIdx.x;
        float sum = red[0][d] + red[1][d] + red[2][d] + red[3][d];
        float sumsq = red[0][4 + d] + red[1][4 + d] + red[2][4 + d] + red[3][4 + d];
        float var = (sumsq - sum * sum / (float)NP) / (float)(NP - 1); // ddof=1
        float stdv = sqrtf(var);
        float pilot = 1.0592f * stdv * N_POW;
        ws[b * ND + d] = 1.0f / pilot;
        ws[32 + b * ND + d] = pilot;
    }
}

__global__ __launch_bounds__(256) void bw_pair_kernel(const float* __restrict__ p,
                                                      float* __restrict__ ws) {
    int tile = blockIdx.x; // 0..NTILES-1
    int b = blockIdx.y;    // 0..NB-1

    __shared__ float4 u[NP];      // scaled particles, 16 KB
    __shared__ float red[4][8];

    float4 ipil = ((const float4*)ws)[b]; // inv_pilot for this batch

    const float4* pb = (const float4*)(p + (size_t)b * NP * ND);
    for (int i = threadIdx.x; i < NP; i += 256) {
        float4 v = pb[i];
        u[i] = make_float4(v.x * ipil.x, v.y * ipil.y, v.z * ipil.z, v.w * ipil.w);
    }
    __syncthreads();

    int il = threadIdx.x & (ITILE - 1);  // 0..31 : which i row in the tile
    int js = threadIdx.x >> 5;           // 0..7  : j stride offset
    int i = tile * ITILE + il;
    float4 ui = u[i];

    float t2x = 0.f, t2y = 0.f, t2z = 0.f, t2w = 0.f;
    float t3x = 0.f, t3y = 0.f, t3z = 0.f, t3w = 0.f;

    for (int j = js; j < NP; j += 8) {
        float4 uj = u[j]; // broadcast within half-wave: conflict-free
        float dxx = uj.x - ui.x;
        float dxy = uj.y - ui.y;
        float dxz = uj.z - ui.z;
        float dxw = uj.w - ui.w;
        float x2x = dxx * dxx, x2y = dxy * dxy, x2z = dxz * dxz, x2w = dxw * dxw;
        float r2 = x2x + x2y + x2z + x2w;
        float k = __expf(-0.5f * r2);
        t2x = fmaf(k, x2x - 1.0f, t2x);
        t2y = fmaf(k, x2y - 1.0f, t2y);
        t2z = fmaf(k, x2z - 1.0f, t2z);
        t2w = fmaf(k, x2w - 1.0f, t2w);
        t3x = fmaf(k * dxx, x2x - 3.0f, t3x);
        t3y = fmaf(k * dxy, x2y - 3.0f, t3y);
        t3z = fmaf(k * dxz, x2z - 3.0f, t3z);
        t3w = fmaf(k * dxw, x2w - 3.0f, t3w);
    }

    float vals[8] = {t2x, t2y, t2z, t2w, t3x, t3y, t3z, t3w};
#pragma unroll
    for (int off = 32; off > 0; off >>= 1) {
#pragma unroll
        for (int k = 0; k < 8; ++k) vals[k] += __shfl_down(vals[k], off, 64);
    }

    int wave = threadIdx.x >> 6;
    int lane = threadIdx.x & 63;
    if (lane == 0) {
#pragma unroll
        for (int k = 0; k < 8; ++k) red[wave][k] = vals[k];
    }
    __syncthreads();

    if (threadIdx.x < 8) {
        int k = threadIdx.x;
        float v = red[0][k] + red[1][k] + red[2][k] + red[3][k];
        ws[WS_PARTIAL + (b * NTILES + tile) * 8 + k] = v;
    }
}

__global__ __launch_bounds__(64) void bw_final_kernel(const float* __restrict__ ws,
                                                      float* __restrict__ out) {
    int t = threadIdx.x;
    if (t >= NB * ND) return;
    int b = t >> 2;
    int d = t & 3;

    float s2 = 0.f, s3 = 0.f;
    for (int blk = 0; blk < NTILES; ++blk) {
        const float* pp = ws + WS_PARTIAL + (b * NTILES + blk) * 8;
        s2 += pp[d];
        s3 += pp[4 + d];
    }

    float pil = ws[32 + t];
    float p2 = pil * pil;
    float p5 = p2 * p2 * pil;       // pilot^5
    float p7 = p5 * p2;             // pilot^7
    const float denom = (float)NP * (float)(NP - 1);

    float I2 = s2 * INV_SQRT_2PI / (p5 * denom);
    float I3 = -s3 * INV_SQRT_2PI / (p7 * denom);

    float J1 = RK / I2;                    // MU2 = 1
    float J2 = 3.0f * I3 / (20.0f * I2);   // MU4=3, MU2=1
    float base = J1 / (float)NP;

    float ab = fabsf(base);
    float sg = (base > 0.f) ? 1.0f : ((base < 0.f) ? -1.0f : 0.0f);
    float bw1 = sg * powf(ab, 0.2f);
    float bw2 = sg * powf(ab, 0.6f) * J2;
    out[t] = bw1 + bw2;
}

extern "C" void kernel_launch(void* const* d_in, const int* in_sizes, int n_in,
                              void* d_out, int out_size, void* d_ws, size_t ws_size,
                              hipStream_t stream) {
    const float* particles = (const float*)d_in[0];
    // d_in[1] (weights) is unused by the reference
    float* out = (float*)d_out;
    float* ws = (float*)d_ws;

    bw_stats_kernel<<<dim3(NB), dim3(256), 0, stream>>>(particles, ws);
    bw_pair_kernel<<<dim3(NTILES, NB), dim3(256), 0, stream>>>(particles, ws);
    bw_final_kernel<<<dim3(1), dim3(64), 0, stream>>>(ws, out);
}